// Round 7
// baseline (334.121 us; speedup 1.0000x reference)
//
#include <hip/hip_runtime.h>

typedef unsigned short u16;
typedef __attribute__((ext_vector_type(8))) short s8;   // 8 bf16 (4 VGPR) MFMA frag
typedef __attribute__((ext_vector_type(4))) float f4;   // 4 f32 acc frag

#define B_  8
#define C_  64
#define H_  128
#define W_  128
#define HW_ (H_*W_)
#define PITCH 72     // LDS shorts per pixel (144 B rows, 16B-aligned, uniform bank spread)
#define WSZ 36864    // elems of one transformed weight tensor [9][64][64]

// f32 -> bf16 bits, round-to-nearest-even (finite only)
static __device__ __forceinline__ u16 f2bu(float f) {
    union { float f; unsigned u; } c; c.f = f;
    unsigned u = c.u;
    u += 0x7fffu + ((u >> 16) & 1u);
    return (u16)(u >> 16);
}
static __device__ __forceinline__ float bu2f(u16 u) {
    union { unsigned u; float f; } c; c.u = ((unsigned)u) << 16; return c.f;
}

// ---------- transpose+cast: [b][c][h][w] f32 -> [b][h][w][c] bf16 ----------
__global__ __launch_bounds__(256) void transpose2(
    const float* __restrict__ x, const float* __restrict__ edge,
    u16* __restrict__ x_t, u16* __restrict__ edge_t)
{
    __shared__ float s[16][68];
    const int t  = threadIdx.x;
    const int h  = blockIdx.x >> 3;
    const int w0 = (blockIdx.x & 7) * 16;
    const int b  = blockIdx.y;
    const float* src = blockIdx.z ? edge : x;
    u16* dst = blockIdx.z ? edge_t : x_t;
    {
        int c = t >> 2, wq = t & 3;
        float4 v = *(const float4*)(src + ((size_t)b*C_ + c)*HW_ + h*W_ + w0 + wq*4);
        s[wq*4+0][c] = v.x; s[wq*4+1][c] = v.y; s[wq*4+2][c] = v.z; s[wq*4+3][c] = v.w;
    }
    __syncthreads();
    {
        int w = t >> 4, cg = t & 15;
        float4 v = *(const float4*)(&s[w][cg*4]);
        ushort4 o; o.x = f2bu(v.x); o.y = f2bu(v.y); o.z = f2bu(v.z); o.w = f2bu(v.w);
        *(ushort4*)(dst + ((size_t)b*HW_ + h*W_ + w0 + w)*64 + cg*4) = o;
    }
}

// ---------- weight transform: 4x [o][c][3][3] f32 -> [cid][p][o][c] bf16 ----------
__global__ __launch_bounds__(256) void wt_all(
    const float* __restrict__ w0, const float* __restrict__ w1,
    const float* __restrict__ w2, const float* __restrict__ w3,
    u16* __restrict__ dst)
{
    int idx = blockIdx.x*256 + threadIdx.x;            // 0..36863
    int cid = blockIdx.y;
    const float* w = (cid == 0) ? w0 : (cid == 1) ? w1 : (cid == 2) ? w2 : w3;
    int p = idx >> 12, o = (idx >> 6) & 63, c = idx & 63;
    dst[(size_t)cid*WSZ + idx] = f2bu(w[((size_t)o*64 + c)*9 + p]);
}

// ---------- stage an 18x18 halo tile of NHWC bf16 into LDS ----------
static __device__ __forceinline__ void stage_tile(
    u16* __restrict__ s_t, const u16* __restrict__ src, int b, int th0, int tw0, int t)
{
    for (int i = t; i < 18*18*8; i += 256) {
        int pix = i >> 3, ch = i & 7;
        int rr = pix / 18, ww = pix - rr*18;
        int gr = th0 + rr - 1, gw = tw0 + ww - 1;
        uint4 v = {0u,0u,0u,0u};
        if ((unsigned)gr < (unsigned)H_ && (unsigned)gw < (unsigned)W_)
            v = *(const uint4*)(src + ((size_t)b*HW_ + gr*W_ + gw)*64 + ch*8);
        *(uint4*)(&s_t[pix*PITCH + ch*8]) = v;
    }
}

// conv core: D = sum_p [kern_p ⊙] W_p[64och,64c] x X_p[64c,256px], f32 acc, bias init.
// wave wv owns pixel rows wv*4 + nf. (identical to round-5 verified code; s_k now bf16)
template<bool PAC>
static __device__ __forceinline__ void conv_core(
    const u16* __restrict__ s_t, const u16* __restrict__ s_k,
    const u16* __restrict__ w, const float* __restrict__ bias,
    f4 acc[4][4], int wv, int ln, int quad)
{
#pragma unroll
    for (int mf = 0; mf < 4; ++mf) {
        f4 bv;
#pragma unroll
        for (int r = 0; r < 4; ++r) bv[r] = bias[mf*16 + quad*4 + r];
#pragma unroll
        for (int nf = 0; nf < 4; ++nf) acc[mf][nf] = bv;
    }

#pragma unroll
    for (int p = 0; p < 9; ++p) {
        const int dr = p / 3, dc = p - dr*3;
        s8 a[4][2];
#pragma unroll
        for (int mf = 0; mf < 4; ++mf)
#pragma unroll
            for (int kc = 0; kc < 2; ++kc)
                a[mf][kc] = *(const s8*)(w + (((size_t)p*64 + mf*16 + ln)*64 + kc*32 + quad*8));
        s8 bfr[4][2];
#pragma unroll
        for (int nf = 0; nf < 4; ++nf) {
            const u16* base = &s_t[((wv*4 + nf + dr)*18 + ln + dc)*PITCH];
#pragma unroll
            for (int kc = 0; kc < 2; ++kc)
                bfr[nf][kc] = *(const s8*)(base + kc*32 + quad*8);
        }
        if (PAC) {
            float kv[4];
#pragma unroll
            for (int nf = 0; nf < 4; ++nf)
                kv[nf] = bu2f(s_k[p*256 + (wv*4 + nf)*16 + ln]);
#pragma unroll
            for (int mf = 0; mf < 4; ++mf)
#pragma unroll
                for (int nf = 0; nf < 4; ++nf) {
                    f4 d = {0.f, 0.f, 0.f, 0.f};
                    d = __builtin_amdgcn_mfma_f32_16x16x32_bf16(a[mf][0], bfr[nf][0], d, 0, 0, 0);
                    d = __builtin_amdgcn_mfma_f32_16x16x32_bf16(a[mf][1], bfr[nf][1], d, 0, 0, 0);
                    acc[mf][nf] += kv[nf] * d;
                }
        } else {
#pragma unroll
            for (int mf = 0; mf < 4; ++mf)
#pragma unroll
                for (int nf = 0; nf < 4; ++nf) {
                    acc[mf][nf] = __builtin_amdgcn_mfma_f32_16x16x32_bf16(a[mf][0], bfr[nf][0], acc[mf][nf], 0, 0, 0);
                    acc[mf][nf] = __builtin_amdgcn_mfma_f32_16x16x32_bf16(a[mf][1], bfr[nf][1], acc[mf][nf], 0, 0, 0);
                }
        }
    }
}

// epilogue: bf16 NHWC with relu (stage 1)
static __device__ __forceinline__ void store_t(
    u16* __restrict__ out, f4 acc[4][4], int b, int th0, int tw0, int wv, int ln, int quad)
{
#pragma unroll
    for (int mf = 0; mf < 4; ++mf)
#pragma unroll
        for (int nf = 0; nf < 4; ++nf) {
            f4 v = acc[mf][nf];
            ushort4 o;
            o.x = f2bu(fmaxf(v[0], 0.f)); o.y = f2bu(fmaxf(v[1], 0.f));
            o.z = f2bu(fmaxf(v[2], 0.f)); o.w = f2bu(fmaxf(v[3], 0.f));
            size_t pix = (size_t)b*HW_ + (th0 + wv*4 + nf)*W_ + tw0 + ln;
            *(ushort4*)(out + pix*64 + mf*16 + quad*4) = o;
        }
}

// epilogue: f32 NCHW + residual from bf16 NHWC (stage 2)
static __device__ __forceinline__ void store_f(
    float* __restrict__ out, const u16* __restrict__ resid_t,
    f4 acc[4][4], int b, int th0, int tw0, int wv, int ln, int quad)
{
#pragma unroll
    for (int mf = 0; mf < 4; ++mf)
#pragma unroll
        for (int nf = 0; nf < 4; ++nf) {
            size_t pix = (size_t)b*HW_ + (th0 + wv*4 + nf)*W_ + tw0 + ln;
            ushort4 rv = *(const ushort4*)(resid_t + pix*64 + mf*16 + quad*4);
            float rr[4] = {bu2f(rv.x), bu2f(rv.y), bu2f(rv.z), bu2f(rv.w)};
#pragma unroll
            for (int r = 0; r < 4; ++r) {
                int och = mf*16 + quad*4 + r;
                out[((size_t)b*C_ + och)*HW_ + (th0 + wv*4 + nf)*W_ + tw0 + ln]
                    = acc[mf][nf][r] + rr[r];
            }
        }
}

// ---------- fused stage: gauss(inA) + convA(plain, inA) + convB(PAC, inB | guide=inA) ----------
// 16x16 tiles (round-5 verified structure). LDS = 46656 (tile) + 4608 (bf16 s_k)
// = 51264 B -> 3 blocks/CU (was 2 at round-5's 55.9 KB). VGPR cap at 3 waves/EU
// is 168 >= the 128 this kernel used at bound 2 -> no new spill pressure.
template<bool STAGE1>
__global__ __launch_bounds__(256, 3) void fused_stage(
    const u16* __restrict__ inA_t, const u16* __restrict__ inB_t,
    const u16* __restrict__ wA, const u16* __restrict__ wB,
    const float* __restrict__ biasA, const float* __restrict__ biasB,
    const u16* __restrict__ residA_t, const u16* __restrict__ residB_t,
    u16* __restrict__ outA_t, u16* __restrict__ outB_t,
    float* __restrict__ outA_f, float* __restrict__ outB_f)
{
    __shared__ u16 s_t[18*18*PITCH];   // 46656 B
    __shared__ u16 s_k[9*16*16];       //  4608 B (bf16 kern)

    const int t    = threadIdx.x;
    const int b    = blockIdx.y;
    const int th0  = (blockIdx.x >> 3) * 16;
    const int tw0  = (blockIdx.x & 7) * 16;
    const int wv   = t >> 6;
    const int lane = t & 63;
    const int ln   = lane & 15;
    const int quad = lane >> 4;

    // ---- phase 1: stage guide/inA tile ----
    stage_tile(s_t, inA_t, b, th0, tw0, t);
    __syncthreads();

    // ---- phase 2a: gaussian kernel from inA tile -> s_k (one pixel per thread) ----
    {
        const int px = t & 15, py = t >> 4;
        float d2[9];
#pragma unroll
        for (int p = 0; p < 9; ++p) d2[p] = 0.f;
        const u16* cb = &s_t[((py+1)*18 + (px+1))*PITCH];
#pragma unroll 1
        for (int co = 0; co < 8; ++co) {
            s8 c8 = *(const s8*)(cb + co*8);
            float cf[8];
#pragma unroll
            for (int j = 0; j < 8; ++j) cf[j] = bu2f((u16)c8[j]);
#pragma unroll
            for (int p = 0; p < 9; ++p) {
                s8 n8 = *(const s8*)(&s_t[((py + p/3)*18 + px + p%3)*PITCH + co*8]);
#pragma unroll
                for (int j = 0; j < 8; ++j) {
                    float d = bu2f((u16)n8[j]) - cf[j];
                    d2[p] += d * d;
                }
            }
        }
#pragma unroll
        for (int p = 0; p < 9; ++p)
            s_k[p*256 + py*16 + px] = f2bu(__expf(-0.5f * d2[p]));
    }

    // ---- phase 2b: convA (plain) on inA tile ----
    {
        f4 acc[4][4];
        conv_core<false>(s_t, nullptr, wA, biasA, acc, wv, ln, quad);
        if (STAGE1) store_t(outA_t, acc, b, th0, tw0, wv, ln, quad);
        else        store_f(outA_f, residA_t, acc, b, th0, tw0, wv, ln, quad);
    }

    // ---- phase 3: restage with inB tile (syncs also order s_k before convB) ----
    __syncthreads();
    stage_tile(s_t, inB_t, b, th0, tw0, t);
    __syncthreads();

    // ---- phase 4: convB (PAC with s_k) on inB tile ----
    {
        f4 acc[4][4];
        conv_core<true>(s_t, s_k, wB, biasB, acc, wv, ln, quad);
        if (STAGE1) store_t(outB_t, acc, b, th0, tw0, wv, ln, quad);
        else        store_f(outB_f, residB_t, acc, b, th0, tw0, wv, ln, quad);
    }
}

extern "C" void kernel_launch(void* const* d_in, const int* in_sizes, int n_in,
                              void* d_out, int out_size, void* d_ws, size_t ws_size,
                              hipStream_t stream)
{
    const float* x      = (const float*)d_in[0];
    const float* edge   = (const float*)d_in[1];
    const float* w_pac1 = (const float*)d_in[2];
    const float* b_pac1 = (const float*)d_in[3];
    const float* w_pac2 = (const float*)d_in[4];
    const float* b_pac2 = (const float*)d_in[5];
    const float* w_e1   = (const float*)d_in[6];
    const float* b_e1   = (const float*)d_in[7];
    const float* w_e2   = (const float*)d_in[8];
    const float* b_e2   = (const float*)d_in[9];

    float* out_sr   = (float*)d_out;
    float* out_edge = out_sr + (size_t)B_*C_*HW_;

    const size_t NT = (size_t)B_*HW_*64;
    // ws (67.4 MB, proven within ws_size in rounds 5): all intermediates here.
    u16* x_t         = (u16*)d_ws;
    u16* edge_t      = x_t + NT;
    u16* res_edge1_t = edge_t + NT;
    u16* res_sr1_t   = res_edge1_t + NT;
    u16* w_t         = res_sr1_t + NT;    // [4][9][64][64]: 0=e1, 1=pac1, 2=e2, 3=pac2

    dim3 blk(256);

    transpose2<<<dim3(H_*8, B_, 2), blk, 0, stream>>>(x, edge, x_t, edge_t);
    wt_all<<<dim3(144, 4), blk, 0, stream>>>(w_e1, w_pac1, w_e2, w_pac2, w_t);

    dim3 cgrid(64, B_);   // 64 tiles x 8 batches = 512 blocks

    // stage 1: gauss(edge)=kern1 (LDS-only) + conv_e1(edge) + pac1(x)
    fused_stage<true ><<<cgrid, blk, 0, stream>>>(
        edge_t, x_t, w_t + 0*WSZ, w_t + 1*WSZ, b_e1, b_pac1,
        nullptr, nullptr, res_edge1_t, res_sr1_t, nullptr, nullptr);
    // stage 2: gauss(res_edge1)=kern2 + conv_e2(res_edge1)+edge_resid + pac2(res_sr1)+x_resid
    fused_stage<false><<<cgrid, blk, 0, stream>>>(
        res_edge1_t, res_sr1_t, w_t + 2*WSZ, w_t + 3*WSZ, b_e2, b_pac2,
        edge_t, x_t, nullptr, nullptr, out_edge, out_sr);
}